// Round 19
// baseline (77.272 us; speedup 1.0000x reference)
//
#include <hip/hip_runtime.h>

#define BR 64
#define EC 131072
#define CAP 12288
#define LCAP 1024
#define CHUNKS 16
#define CHUNK_V (EC / CHUNKS / 4)   // float4 per chunk = 2048
#define NSCH 41
#define NS (NSCH * 64)              // 2624 samples per row
#define SSTRIDE 3197                // 40*3197+63 = 127943 < EC
#define BINS 4096
#define BD 512                      // kB block size (8 waves)

typedef float nf4 __attribute__((ext_vector_type(4)));

// ws word-offset layout
#define WS_GMAX 0
#define WS_CCNT 264    // +row   (zeroed region: [0,1024))
#define WS_NPOS 640    // +row
#define WS_BMAX 1024   // +1024 per-block maxima (written unconditionally)
#define WS_TLO 2048    // +row   (outside zeroed region; written unconditionally)
#define CAND_U_OFF 4096
#define CAND_I_OFF (CAND_U_OFF + BR * CAP)

// Monotonic float->uint mapping (order-preserving, bijective)
__device__ __forceinline__ unsigned map_f(float f) {
    unsigned b = __float_as_uint(f);
    return (b & 0x80000000u) ? ~b : (b | 0x80000000u);
}
__device__ __forceinline__ float unmap_f(unsigned u) {
    unsigned b = (u & 0x80000000u) ? (u & 0x7FFFFFFFu) : ~u;
    return __uint_as_float(b);
}

// EXACT numpy-op-sequence value computation; contract(off) -> bit-identical everywhere.
__device__ __forceinline__ void compute_vals(float x, float bt, float gmax, float bp,
                                             float* nb, float* bo) {
#pragma clang fp contract(off)
    float q = x / gmax;
    float t = 1.0f - q;
    float p = t * bp;
    float nbv = bt + p;
    *nb = nbv;
    *bo = fmaxf(x, 0.0f) + nbv;
}

__device__ __forceinline__ unsigned umax_(unsigned a, unsigned b) { return a > b ? a : b; }
__device__ __forceinline__ unsigned umin_(unsigned a, unsigned b) { return a < b ? a : b; }

__device__ __forceinline__ unsigned calc_K(const float* sp) {
    unsigned K = (unsigned)ceilf(sp[1] * (float)EC);
    if (K > EC) K = EC;
    if (K == 0) K = 1;
    return K;
}

// Radix select (descending rank K) over n values in LDS array su. 256 threads.
__device__ unsigned lds_radix_select(const unsigned* su, unsigned n, unsigned K,
                                     unsigned* hist, unsigned* scan, unsigned* sb,
                                     int t, unsigned* krem) {
    unsigned pv = 0, Kp = K;
    for (int pass = 0; pass < 4; ++pass) {
        int shift = 24 - 8 * pass;
        hist[t] = 0;
        __syncthreads();
        for (unsigned i = t; i < n; i += 256) {
            unsigned u = su[i];
            bool match = (pass == 0) || ((u >> (shift + 8)) == (pv >> (shift + 8)));
            if (match) atomicAdd(&hist[(u >> shift) & 0xFFu], 1u);
        }
        __syncthreads();
        unsigned my = hist[t];
        scan[t] = my;
        __syncthreads();
        for (int off = 1; off < 256; off <<= 1) {
            unsigned v = (t + off < 256) ? scan[t + off] : 0u;
            __syncthreads();
            scan[t] += v;
            __syncthreads();
        }
        unsigned incl = scan[t], excl = incl - my;
        if (excl < Kp && incl >= Kp) {
            sb[0] = pv | ((unsigned)t << shift);
            sb[1] = Kp - excl;
        }
        __syncthreads();
        pv = sb[0];
        Kp = sb[1];
        __syncthreads();
    }
    *krem = Kp;
    return pv;
}

// Exact full-row select on bo (USE_NB=0) or nb (USE_NB=1). 256 threads.
template<int USE_NB>
__device__ unsigned row_select_full(const float* xr, const float* br, float gmax,
                                    float bp, unsigned K, unsigned* hist,
                                    unsigned* aux, int t, unsigned* cut_out) {
    unsigned prefix = 0, Kp = K;
    for (int pass = 0; pass < 4; ++pass) {
        int shift = 24 - 8 * pass;
        hist[t] = 0;
        __syncthreads();
        for (int i = t; i < EC; i += 256) {
            float nb, bo;
            compute_vals(xr[i], br[i], gmax, bp, &nb, &bo);
            unsigned u = map_f(USE_NB ? nb : bo);
            bool match = (pass == 0) || ((u >> (shift + 8)) == (prefix >> (shift + 8)));
            if (match) atomicAdd(&hist[(u >> shift) & 0xFFu], 1u);
        }
        __syncthreads();
        if (t == 0) {
            unsigned cum = 0, bsel = 0, kr = Kp;
            for (int b = 255; b >= 0; --b) {
                unsigned h = hist[b];
                if (cum + h >= Kp) { bsel = (unsigned)b; kr = Kp - cum; break; }
                cum += h;
            }
            aux[0] = prefix | (bsel << shift);
            aux[1] = kr;
        }
        __syncthreads();
        prefix = aux[0];
        Kp = aux[1];
        __syncthreads();
    }
    unsigned u_t = prefix, ties = Kp;
    if (t == 0) { aux[6] = 0; aux[7] = 0xFFFFFFFFu; }
    __syncthreads();
    int wid = t >> 6, lane = t & 63;
    for (int base0 = 0; base0 < EC; base0 += 256) {
        int i = base0 + t;
        float nb, bo;
        compute_vals(xr[i], br[i], gmax, bp, &nb, &bo);
        bool eq = (map_f(USE_NB ? nb : bo) == u_t);
        unsigned long long bal = __ballot(eq);
        if (lane == 0) aux[2 + wid] = (unsigned)__popcll(bal);
        __syncthreads();
        unsigned run = aux[6];
        unsigned wpre = 0;
        for (int w = 0; w < wid; ++w) wpre += aux[2 + w];
        if (eq) {
            unsigned r = run + wpre + (unsigned)__popcll(bal & ((1ull << lane) - 1ull));
            if (r == ties - 1) aux[7] = (unsigned)i;
        }
        __syncthreads();
        if (t == 0) aux[6] = run + aux[2] + aux[3] + aux[4] + aux[5];
        __syncthreads();
        if (aux[6] >= ties) break;
    }
    if (t == 0) *cut_out = aux[7];
    __syncthreads();
    return u_t;
}

// ---- Kernel A: zero header + per-block max; blocks 0..63 also compute per-row
// surrogate-key sample threshold (no gmax needed: boost term <= 2e-8 << bin width;
// one extra bin down absorbs it; kC's exact fallback guards all other data).
__global__ __launch_bounds__(256) void kA(const float* __restrict__ x,
                                          const float* __restrict__ bt,
                                          const float* __restrict__ sp,
                                          unsigned* __restrict__ ws) {
    __shared__ unsigned hist[BINS];
    __shared__ unsigned ssum[256], sabove[256];
    __shared__ unsigned sm[4];
    __shared__ unsigned sb1;
    int t = threadIdx.x;
    if (blockIdx.x == 0)
        for (int i = t; i < 1024; i += 256) ws[i] = 0u;
    // grid-stride max over x
    const float4* x4 = (const float4*)x;
    unsigned m = 0;
    const int nvec = BR * EC / 4;
    int stride = gridDim.x * 256;
    for (int v = blockIdx.x * 256 + t; v < nvec; v += stride) {
        float4 xv = x4[v];
        m = umax_(m, map_f(xv.x)); m = umax_(m, map_f(xv.y));
        m = umax_(m, map_f(xv.z)); m = umax_(m, map_f(xv.w));
    }
    for (int off = 32; off; off >>= 1) m = umax_(m, __shfl_down(m, off, 64));
    if ((t & 63) == 0) sm[t >> 6] = m;
    __syncthreads();
    if (t == 0)
        ws[WS_BMAX + blockIdx.x] = umax_(umax_(sm[0], sm[1]), umax_(sm[2], sm[3]));

    if (blockIdx.x >= BR) return;
    // ---- per-row sample threshold (surrogate key, no gmax) ----
    int row = blockIdx.x;
    for (int i = t; i < BINS; i += 256) hist[i] = 0;
    if (t == 0) sb1 = 0;
    __syncthreads();
    const float* xr = x + (size_t)row * EC;
    const float* br = bt + (size_t)row * EC;
    for (int s = t; s < NS; s += 256) {
        int idx = (s >> 6) * SSTRIDE + (s & 63);
        float sv = fmaxf(xr[idx], 0.0f) + br[idx];   // surrogate: boost omitted
        atomicAdd(&hist[map_f(sv) >> 20], 1u);
    }
    __syncthreads();
    unsigned K = calc_K(sp);
    unsigned R = (unsigned)ceilf(1.75f * (float)NS * (float)K / (float)EC);
    if (R < 32) R = 32;
    if (R > NS) R = NS;
    unsigned hv[16];
    unsigned s = 0;
    #pragma unroll
    for (int j = 0; j < 16; ++j) { hv[j] = hist[t * 16 + j]; s += hv[j]; }
    ssum[t] = s;
    __syncthreads();
    if (t == 0) {
        unsigned acc = 0;
        for (int q = 255; q >= 0; --q) { sabove[q] = acc; acc += ssum[q]; }
    }
    __syncthreads();
    unsigned cum = sabove[t];
    for (int j = 15; j >= 0; --j) {
        unsigned h = hv[j];
        if (cum < R && cum + h >= R) sb1 = (unsigned)(t * 16 + j);
        cum += h;
    }
    __syncthreads();
    if (t == 0) {
        unsigned b1 = sb1;
        // one extra bin down: u > tlo  <=>  u >= (b1-1) bin lower edge
        ws[WS_TLO + row] = (b1 >= 1) ? (((b1 - 1) << 20) - 1u) : 0u;
    }
}

// -------- Kernel B: gmax reduce + collect + npos + DEFAULT outputs (no sampling) --
__global__ __launch_bounds__(BD) void kB(const float* __restrict__ x,
                                         const float* __restrict__ bt,
                                         const float* __restrict__ bp_p,
                                         unsigned* __restrict__ ws,
                                         float4* __restrict__ out4,
                                         float4* __restrict__ fb4) {
    __shared__ unsigned lu[LCAP], li[LCAP];       // 8KB
    __shared__ unsigned sred[8];
    __shared__ unsigned slcnt, sgbase;
    int t = threadIdx.x;
    int lane = t & 63;
    int row = blockIdx.x >> 4, chunk = blockIdx.x & (CHUNKS - 1);

    // gmax from 1024 per-block maxima (redundant per block; L2-hot)
    unsigned m = 0;
    for (int i = t; i < 1024; i += BD) m = umax_(m, ws[WS_BMAX + i]);
    for (int off = 32; off; off >>= 1) m = umax_(m, __shfl_down(m, off, 64));
    if (lane == 0) sred[t >> 6] = m;
    if (t == 0) slcnt = 0;
    __syncthreads();
    unsigned gmu = 0;
    #pragma unroll
    for (int w = 0; w < BD / 64; ++w) gmu = umax_(gmu, sred[w]);
    if (blockIdx.x == 0 && t == 0) ws[WS_GMAX] = gmu;
    float gmax = unmap_f(gmu);
    float bp = *bp_p;
    unsigned tlo = ws[WS_TLO + row];

    // stream: collect candidates (wave-aggregated) + npos + default outputs
    const float4* x4 = (const float4*)x;
    const float4* bt4 = (const float4*)bt;
    unsigned* cu = ws + CAND_U_OFF + (size_t)row * CAP;
    unsigned* ci = ws + CAND_I_OFF + (size_t)row * CAP;
    size_t base = (size_t)row * (EC / 4) + (size_t)chunk * CHUNK_V;
    int ebase = chunk * (EC / CHUNKS);
    const float4 zo = make_float4(0.0f, 0.0f, 0.0f, 0.0f);
    unsigned posc = 0;
    for (int v = t; v < CHUNK_V; v += BD) {
        float4 xv = x4[base + v];
        float4 bv = bt4[base + v];
        float xs[4] = {xv.x, xv.y, xv.z, xv.w};
        float bs[4] = {bv.x, bv.y, bv.z, bv.w};
        float4 fv;
        unsigned uj[4];
        float nb0, nb1, nb2, nb3, bo_;
        compute_vals(xs[0], bs[0], gmax, bp, &nb0, &bo_); uj[0] = map_f(bo_);
        compute_vals(xs[1], bs[1], gmax, bp, &nb1, &bo_); uj[1] = map_f(bo_);
        compute_vals(xs[2], bs[2], gmax, bp, &nb2, &bo_); uj[2] = map_f(bo_);
        compute_vals(xs[3], bs[3], gmax, bp, &nb3, &bo_); uj[3] = map_f(bo_);
        fv = make_float4(nb0, nb1, nb2, nb3);
        #pragma unroll
        for (int j = 0; j < 4; ++j) posc += (uj[j] > 0x80000000u) ? 1u : 0u;
        out4[base + v] = zo;
        fb4[base + v] = fv;
        #pragma unroll
        for (int j = 0; j < 4; ++j) {
            bool match = (uj[j] > tlo);
            unsigned long long bal = __ballot(match);
            if (bal) {
                int leader = (int)(__ffsll((long long)bal) - 1);
                unsigned cnt = (unsigned)__popcll(bal);
                unsigned b0 = 0;
                if (lane == leader) b0 = atomicAdd(&slcnt, cnt);
                unsigned wbase = __shfl(b0, leader, 64);
                if (match) {
                    unsigned p = wbase + (unsigned)__popcll(bal & ((1ull << lane) - 1ull));
                    unsigned idx = (unsigned)(ebase + v * 4 + j);
                    if (p < LCAP) {
                        lu[p] = uj[j]; li[p] = idx;
                    } else {  // overflow fallback (rare)
                        unsigned gp = atomicAdd(&ws[WS_CCNT + row], 1u);
                        if (gp < CAP) { cu[gp] = uj[j]; ci[gp] = idx; }
                    }
                }
            }
        }
    }
    for (int off = 32; off; off >>= 1) posc += __shfl_down(posc, off, 64);
    if (lane == 0) sred[t >> 6] = posc;
    __syncthreads();
    if (t == 0) {
        unsigned tot = 0;
        #pragma unroll
        for (int w = 0; w < BD / 64; ++w) tot += sred[w];
        atomicAdd(&ws[WS_NPOS + row], tot);
    }
    __syncthreads();
    unsigned n = slcnt < LCAP ? slcnt : LCAP;
    if (t == 0) sgbase = atomicAdd(&ws[WS_CCNT + row], n);
    __syncthreads();
    unsigned gb = sgbase;
    for (unsigned i = t; i < n; i += BD) {
        unsigned gp = gb + i;
        if (gp < CAP) { cu[gp] = lu[i]; ci[gp] = li[i]; }
    }
}

// -------- Kernel C: exact rank-K select + tie-cut + scatter-fix + gated correction
// active = sum_r min(K, npos[r])  [exact; proof in round-11 notes]
__global__ __launch_bounds__(256) void kC(const float* __restrict__ x,
                                          const float* __restrict__ bt,
                                          const float* __restrict__ sp,
                                          const float* __restrict__ bp_p,
                                          unsigned* __restrict__ ws,
                                          float* __restrict__ out,
                                          float* __restrict__ fb) {
    int row = blockIdx.x;
    int t = threadIdx.x;
    unsigned n = ws[WS_CCNT + row];
    unsigned K = calc_K(sp);
    float gmax = unmap_f(ws[WS_GMAX]);
    float bp = *bp_p;
    const float* xr = x + (size_t)row * EC;
    const float* br = bt + (size_t)row * EC;
    float* outr = out + (size_t)row * EC;
    float* fbr = fb + (size_t)row * EC;
    __shared__ unsigned su[CAP];                  // 48KB
    __shared__ unsigned hist[256], scan[256], sb[2];
    __shared__ unsigned marr[256];
    __shared__ unsigned mcnt;
    __shared__ unsigned aux[8];
    __shared__ unsigned sact, scut;
    if (n >= K && n <= CAP) {
        const unsigned* cu = ws + CAND_U_OFF + (size_t)row * CAP;
        const unsigned* ci = ws + CAND_I_OFF + (size_t)row * CAP;
        for (unsigned i = t; i < n; i += 256) su[i] = cu[i];
        if (t == 0) mcnt = 0;
        __syncthreads();
        unsigned krem2;
        unsigned u_t = lds_radix_select(su, n, K, hist, scan, sb, t, &krem2);
        for (unsigned i = t; i < n; i += 256)
            if (su[i] == u_t) {
                unsigned p = atomicAdd(&mcnt, 1u);
                if (p < 256) marr[p] = ci[i];
            }
        __syncthreads();
        unsigned m = mcnt;
        if (m <= 256) {
            for (unsigned i = t; i < m; i += 256) {
                unsigned myidx = marr[i];
                unsigned r = 0;
                for (unsigned j = 0; j < m; ++j) r += (marr[j] < myidx) ? 1u : 0u;
                if (r == krem2 - 1) scut = myidx;
            }
        } else {  // pathological tie overflow: correct slow path
            for (unsigned i = t; i < n; i += 256) {
                if (su[i] == u_t) {
                    unsigned myidx = ci[i];
                    unsigned r = 0;
                    for (unsigned j = 0; j < n; ++j)
                        if (su[j] == u_t && ci[j] < myidx) ++r;
                    if (r == krem2 - 1) scut = myidx;
                }
            }
        }
        __syncthreads();
        unsigned cut = scut;
        for (unsigned i = t; i < n; i += 256) {
            unsigned u = su[i], idx = ci[i];
            bool sel = (u > u_t) || ((u == u_t) && (idx <= cut));
            if (sel && u > 0x80000000u) { outr[idx] = 1.0f; fbr[idx] = 0.0f; }
        }
    } else {
        // estimate failed (never for this data): exact full-row select + full fix
        unsigned u_t = row_select_full<0>(xr, br, gmax, bp, K, hist, aux, t, &scut);
        unsigned cut = scut;
        for (int i = t; i < EC; i += 256) {
            float nb, bo;
            compute_vals(xr[i], br[i], gmax, bp, &nb, &bo);
            unsigned u = map_f(bo);
            bool sel = (u > u_t) || ((u == u_t) && ((unsigned)i <= cut));
            if (sel && u > 0x80000000u) { outr[i] = 1.0f; fbr[i] = 0.0f; }
        }
    }

    // ---- global active + gated correction branch (dead for this input) ----
    unsigned act = 0;
    if (t < 64) act = umin_(K, ws[WS_NPOS + t]);
    for (int off = 32; off; off >>= 1) act += __shfl_down(act, off, 64);
    if (t == 0) sact = act;
    __syncthreads();
    float active = (float)sact;
    float min_active = floorf(sp[0] * (float)EC);
    if (active < min_active) {
        unsigned K2 = (unsigned)ceilf(min_active - active);
        if (K2 > EC) K2 = EC;
        unsigned ut2 = row_select_full<1>(xr, br, gmax, bp, K2, hist, aux, t, &scut);
        unsigned cut2 = scut;
        for (int i = t; i < EC; i += 256) {
            float nb, bo;
            compute_vals(xr[i], br[i], gmax, bp, &nb, &bo);
            unsigned u2 = map_f(nb);
            if (u2 > ut2 || (u2 == ut2 && (unsigned)i <= cut2)) {
                outr[i] = 1.0f;
                fbr[i] = 0.0f;
            }
        }
    }
}

extern "C" void kernel_launch(void* const* d_in, const int* in_sizes, int n_in,
                              void* d_out, int out_size, void* d_ws, size_t ws_size,
                              hipStream_t stream) {
    const float* x  = (const float*)d_in[0];
    const float* bt = (const float*)d_in[1];
    const float* sp = (const float*)d_in[2];
    const float* bp = (const float*)d_in[3];
    float* out = (float*)d_out;
    float* fb  = out + (size_t)BR * EC;
    unsigned* ws = (unsigned*)d_ws;

    kA<<<1024, 256, 0, stream>>>(x, bt, sp, ws);
    kB<<<BR * CHUNKS, BD, 0, stream>>>(x, bt, bp, ws, (float4*)out, (float4*)fb);
    kC<<<BR, 256, 0, stream>>>(x, bt, sp, bp, ws, out, fb);
}

// Round 20
// 72.578 us; speedup vs baseline: 1.0647x; 1.0647x over previous
//
#include <hip/hip_runtime.h>

#define BR 64
#define EC 131072
#define CAP 8192
#define LCAP 1024
#define CHUNKS 16
#define CHUNK_V (EC / CHUNKS / 4)   // float4 per chunk = 2048
#define NSCH 41
#define NS (NSCH * 64)              // 2624 samples per row
#define SSTRIDE 3197                // 40*3197+63 = 127943 < EC
#define BINS 4096
#define BD 512                      // kB block size (8 waves)

typedef float nf4 __attribute__((ext_vector_type(4)));   // native vec for nontemporal

// ws word-offset layout
#define WS_GMAX 0
#define WS_CCNT 264    // +row
#define WS_NPOS 640    // +row (positives per row)
#define WS_BMAX 1024   // +1024 per-block maxima (written unconditionally)
#define CAND_U_OFF 4096
#define CAND_I_OFF (CAND_U_OFF + BR * CAP)

// Monotonic float->uint mapping (order-preserving, bijective)
__device__ __forceinline__ unsigned map_f(float f) {
    unsigned b = __float_as_uint(f);
    return (b & 0x80000000u) ? ~b : (b | 0x80000000u);
}
__device__ __forceinline__ float unmap_f(unsigned u) {
    unsigned b = (u & 0x80000000u) ? (u & 0x7FFFFFFFu) : ~u;
    return __uint_as_float(b);
}

// EXACT numpy-op-sequence value computation; contract(off) so every kernel
// computes bit-identical values.
__device__ __forceinline__ void compute_vals(float x, float bt, float gmax, float bp,
                                             float* nb, float* bo) {
#pragma clang fp contract(off)
    float q = x / gmax;
    float t = 1.0f - q;
    float p = t * bp;
    float nbv = bt + p;
    *nb = nbv;
    *bo = fmaxf(x, 0.0f) + nbv;
}

__device__ __forceinline__ unsigned umax_(unsigned a, unsigned b) { return a > b ? a : b; }
__device__ __forceinline__ unsigned umin_(unsigned a, unsigned b) { return a < b ? a : b; }

__device__ __forceinline__ unsigned calc_K(const float* sp) {
    unsigned K = (unsigned)ceilf(sp[1] * (float)EC);
    if (K > EC) K = EC;
    if (K == 0) K = 1;
    return K;
}

// Radix select (descending rank K) over n values in LDS array su (full 32-bit).
// 256 threads.
__device__ unsigned lds_radix_select(const unsigned* su, unsigned n, unsigned K,
                                     unsigned* hist, unsigned* scan, unsigned* sb,
                                     int t, unsigned* krem) {
    unsigned pv = 0, Kp = K;
    for (int pass = 0; pass < 4; ++pass) {
        int shift = 24 - 8 * pass;
        hist[t] = 0;
        __syncthreads();
        for (unsigned i = t; i < n; i += 256) {
            unsigned u = su[i];
            bool match = (pass == 0) || ((u >> (shift + 8)) == (pv >> (shift + 8)));
            if (match) atomicAdd(&hist[(u >> shift) & 0xFFu], 1u);
        }
        __syncthreads();
        unsigned my = hist[t];
        scan[t] = my;
        __syncthreads();
        for (int off = 1; off < 256; off <<= 1) {
            unsigned v = (t + off < 256) ? scan[t + off] : 0u;
            __syncthreads();
            scan[t] += v;
            __syncthreads();
        }
        unsigned incl = scan[t], excl = incl - my;
        if (excl < Kp && incl >= Kp) {
            sb[0] = pv | ((unsigned)t << shift);
            sb[1] = Kp - excl;
        }
        __syncthreads();
        pv = sb[0];
        Kp = sb[1];
        __syncthreads();
    }
    *krem = Kp;
    return pv;
}

// Exact full-row select on bo (USE_NB=0) or nb (USE_NB=1). 256 threads.
// Returns u_t (uniform); *cut_out (LDS) valid for all threads after return.
template<int USE_NB>
__device__ unsigned row_select_full(const float* xr, const float* br, float gmax,
                                    float bp, unsigned K, unsigned* hist,
                                    unsigned* aux, int t, unsigned* cut_out) {
    unsigned prefix = 0, Kp = K;
    for (int pass = 0; pass < 4; ++pass) {
        int shift = 24 - 8 * pass;
        hist[t] = 0;
        __syncthreads();
        for (int i = t; i < EC; i += 256) {
            float nb, bo;
            compute_vals(xr[i], br[i], gmax, bp, &nb, &bo);
            unsigned u = map_f(USE_NB ? nb : bo);
            bool match = (pass == 0) || ((u >> (shift + 8)) == (prefix >> (shift + 8)));
            if (match) atomicAdd(&hist[(u >> shift) & 0xFFu], 1u);
        }
        __syncthreads();
        if (t == 0) {
            unsigned cum = 0, bsel = 0, kr = Kp;
            for (int b = 255; b >= 0; --b) {
                unsigned h = hist[b];
                if (cum + h >= Kp) { bsel = (unsigned)b; kr = Kp - cum; break; }
                cum += h;
            }
            aux[0] = prefix | (bsel << shift);
            aux[1] = kr;
        }
        __syncthreads();
        prefix = aux[0];
        Kp = aux[1];
        __syncthreads();
    }
    unsigned u_t = prefix, ties = Kp;
    if (t == 0) { aux[6] = 0; aux[7] = 0xFFFFFFFFu; }
    __syncthreads();
    int wid = t >> 6, lane = t & 63;
    for (int base0 = 0; base0 < EC; base0 += 256) {
        int i = base0 + t;
        float nb, bo;
        compute_vals(xr[i], br[i], gmax, bp, &nb, &bo);
        bool eq = (map_f(USE_NB ? nb : bo) == u_t);
        unsigned long long bal = __ballot(eq);
        if (lane == 0) aux[2 + wid] = (unsigned)__popcll(bal);
        __syncthreads();
        unsigned run = aux[6];
        unsigned wpre = 0;
        for (int w = 0; w < wid; ++w) wpre += aux[2 + w];
        if (eq) {
            unsigned r = run + wpre + (unsigned)__popcll(bal & ((1ull << lane) - 1ull));
            if (r == ties - 1) aux[7] = (unsigned)i;
        }
        __syncthreads();
        if (t == 0) aux[6] = run + aux[2] + aux[3] + aux[4] + aux[5];
        __syncthreads();
        if (aux[6] >= ties) break;
    }
    if (t == 0) *cut_out = aux[7];
    __syncthreads();
    return u_t;
}

// ---------------- Kernel A: zero scratch header + per-block max of x --------------
__global__ __launch_bounds__(256) void kA(const float4* __restrict__ x4,
                                          unsigned* __restrict__ ws) {
    if (blockIdx.x == 0)
        for (int i = threadIdx.x; i < 1024; i += 256) ws[i] = 0u;
    unsigned m = 0;
    const int nvec = BR * EC / 4;
    int stride = gridDim.x * 256;
    for (int v = blockIdx.x * 256 + threadIdx.x; v < nvec; v += stride) {
        float4 xv = x4[v];
        m = umax_(m, map_f(xv.x)); m = umax_(m, map_f(xv.y));
        m = umax_(m, map_f(xv.z)); m = umax_(m, map_f(xv.w));
    }
    for (int off = 32; off; off >>= 1) m = umax_(m, __shfl_down(m, off, 64));
    __shared__ unsigned sm[4];
    if ((threadIdx.x & 63) == 0) sm[threadIdx.x >> 6] = m;
    __syncthreads();
    if (threadIdx.x == 0)
        ws[WS_BMAX + blockIdx.x] = umax_(umax_(sm[0], sm[1]), umax_(sm[2], sm[3]));
}

// -------- Kernel B: gmax + sample-threshold + collect + npos + DEFAULT outputs ----
// 512 threads (8 waves): streaming phase wants full occupancy (32 waves/CU cap).
__global__ __launch_bounds__(BD) void kB(const float* __restrict__ x,
                                         const float* __restrict__ bt,
                                         const float* __restrict__ sp,
                                         const float* __restrict__ bp_p,
                                         unsigned* __restrict__ ws,
                                         nf4* __restrict__ out4,
                                         nf4* __restrict__ fb4) {
    __shared__ unsigned hist[BINS];               // 16KB
    __shared__ unsigned lu[LCAP], li[LCAP];       // 8KB
    __shared__ unsigned ssum[256], sabove[256];   // 2KB
    __shared__ unsigned sred[8];
    __shared__ unsigned stlo, slcnt, sgbase;
    int t = threadIdx.x;
    int row = blockIdx.x >> 4, chunk = blockIdx.x & (CHUNKS - 1);

    // 1) gmax from 1024 per-block maxima (redundant per block; L2-hot)
    unsigned m = 0;
    for (int i = t; i < 1024; i += BD) m = umax_(m, ws[WS_BMAX + i]);
    for (int off = 32; off; off >>= 1) m = umax_(m, __shfl_down(m, off, 64));
    if ((t & 63) == 0) sred[t >> 6] = m;
    __syncthreads();
    unsigned gmu = 0;
    #pragma unroll
    for (int w = 0; w < BD / 64; ++w) gmu = umax_(gmu, sred[w]);
    if (blockIdx.x == 0 && t == 0) ws[WS_GMAX] = gmu;
    float gmax = unmap_f(gmu);
    float bp = *bp_p;

    // 2) sample histogram (top-12 bits of u)
    for (int i = t; i < BINS; i += BD) hist[i] = 0;
    if (t == 0) slcnt = 0;
    __syncthreads();
    const float* xr = x + (size_t)row * EC;
    const float* br = bt + (size_t)row * EC;
    for (int s = t; s < NS; s += BD) {
        int idx = (s >> 6) * SSTRIDE + (s & 63);
        float nb, bo;
        compute_vals(xr[idx], br[idx], gmax, bp, &nb, &bo);
        atomicAdd(&hist[map_f(bo) >> 20], 1u);
    }
    __syncthreads();

    // 3) threshold = lower edge of bin holding rank-R sample (conservative)
    unsigned K = calc_K(sp);
    unsigned R = (unsigned)ceilf(1.75f * (float)NS * (float)K / (float)EC);
    if (R < 32) R = 32;
    if (R > NS) R = NS;
    if (t < 256) {
        unsigned hv[16];
        unsigned s = 0;
        #pragma unroll
        for (int j = 0; j < 16; ++j) { hv[j] = hist[t * 16 + j]; s += hv[j]; }
        ssum[t] = s;
        __syncthreads();
        if (t == 0) {
            unsigned acc = 0;
            for (int q = 255; q >= 0; --q) { sabove[q] = acc; acc += ssum[q]; }
        }
        __syncthreads();
        unsigned cum = sabove[t];
        for (int j = 15; j >= 0; --j) {
            unsigned h = hv[j];
            if (cum < R && cum + h >= R) stlo = ((unsigned)(t * 16 + j)) << 20;
            cum += h;
        }
    } else {
        __syncthreads();
        __syncthreads();
    }
    __syncthreads();
    unsigned tlo = stlo ? stlo - 1u : 0u;   // u > tlo  <=>  u >= bin lower edge

    // 4) collect candidates + npos + write default outputs
    const float4* x4 = (const float4*)x;
    const float4* bt4 = (const float4*)bt;
    unsigned* cu = ws + CAND_U_OFF + (size_t)row * CAP;
    unsigned* ci = ws + CAND_I_OFF + (size_t)row * CAP;
    size_t base = (size_t)row * (EC / 4) + (size_t)chunk * CHUNK_V;
    int ebase = chunk * (EC / CHUNKS);
    const nf4 zo = {0.0f, 0.0f, 0.0f, 0.0f};
    unsigned posc = 0;
    for (int v = t; v < CHUNK_V; v += BD) {
        float4 xv = x4[base + v];
        float4 bv = bt4[base + v];
        float xs[4] = {xv.x, xv.y, xv.z, xv.w};
        float bs[4] = {bv.x, bv.y, bv.z, bv.w};
        nf4 fv;
        #pragma unroll
        for (int j = 0; j < 4; ++j) {
            float nb, bo;
            compute_vals(xs[j], bs[j], gmax, bp, &nb, &bo);
            unsigned u = map_f(bo);
            fv[j] = nb;
            posc += (u > 0x80000000u) ? 1u : 0u;
            if (u > tlo) {
                unsigned p = atomicAdd(&slcnt, 1u);
                if (p < LCAP) {
                    lu[p] = u; li[p] = (unsigned)(ebase + v * 4 + j);
                } else {  // overflow fallback (rare)
                    unsigned gp = atomicAdd(&ws[WS_CCNT + row], 1u);
                    if (gp < CAP) { cu[gp] = u; ci[gp] = (unsigned)(ebase + v * 4 + j); }
                }
            }
        }
        __builtin_nontemporal_store(zo, &out4[base + v]);
        __builtin_nontemporal_store(fv, &fb4[base + v]);
    }
    for (int off = 32; off; off >>= 1) posc += __shfl_down(posc, off, 64);
    if ((t & 63) == 0) sred[t >> 6] = posc;
    __syncthreads();
    if (t == 0) {
        unsigned tot = 0;
        #pragma unroll
        for (int w = 0; w < BD / 64; ++w) tot += sred[w];
        atomicAdd(&ws[WS_NPOS + row], tot);
    }
    __syncthreads();
    unsigned n = slcnt < LCAP ? slcnt : LCAP;
    if (t == 0) sgbase = atomicAdd(&ws[WS_CCNT + row], n);
    __syncthreads();
    unsigned gb = sgbase;
    for (unsigned i = t; i < n; i += BD) {
        unsigned gp = gb + i;
        if (gp < CAP) { cu[gp] = lu[i]; ci[gp] = li[i]; }
    }
}

// -------- Kernel C: exact rank-K select + tie-cut + scatter-fix + gated correction
// active = sum_r min(K, npos[r])  [exact: selection picks exactly K; if npos>=K the
// K-th largest is positive -> saved=K; else all positives selected -> saved=npos]
__global__ __launch_bounds__(256) void kC(const float* __restrict__ x,
                                          const float* __restrict__ bt,
                                          const float* __restrict__ sp,
                                          const float* __restrict__ bp_p,
                                          unsigned* __restrict__ ws,
                                          float* __restrict__ out,
                                          float* __restrict__ fb) {
    int row = blockIdx.x;
    int t = threadIdx.x;
    unsigned n = ws[WS_CCNT + row];
    unsigned K = calc_K(sp);
    float gmax = unmap_f(ws[WS_GMAX]);
    float bp = *bp_p;
    const float* xr = x + (size_t)row * EC;
    const float* br = bt + (size_t)row * EC;
    float* outr = out + (size_t)row * EC;
    float* fbr = fb + (size_t)row * EC;
    __shared__ unsigned su[CAP];
    __shared__ unsigned hist[256], scan[256], sb[2];
    __shared__ unsigned marr[256];
    __shared__ unsigned mcnt;
    __shared__ unsigned aux[8];
    __shared__ unsigned sact, scut;
    if (n >= K && n <= CAP) {
        const unsigned* cu = ws + CAND_U_OFF + (size_t)row * CAP;
        const unsigned* ci = ws + CAND_I_OFF + (size_t)row * CAP;
        for (unsigned i = t; i < n; i += 256) su[i] = cu[i];
        if (t == 0) mcnt = 0;
        __syncthreads();
        unsigned krem2;
        unsigned u_t = lds_radix_select(su, n, K, hist, scan, sb, t, &krem2);
        for (unsigned i = t; i < n; i += 256)
            if (su[i] == u_t) {
                unsigned p = atomicAdd(&mcnt, 1u);
                if (p < 256) marr[p] = ci[i];
            }
        __syncthreads();
        unsigned m = mcnt;
        if (m <= 256) {
            for (unsigned i = t; i < m; i += 256) {
                unsigned myidx = marr[i];
                unsigned r = 0;
                for (unsigned j = 0; j < m; ++j) r += (marr[j] < myidx) ? 1u : 0u;
                if (r == krem2 - 1) scut = myidx;
            }
        } else {  // pathological tie overflow: correct slow path
            for (unsigned i = t; i < n; i += 256) {
                if (su[i] == u_t) {
                    unsigned myidx = ci[i];
                    unsigned r = 0;
                    for (unsigned j = 0; j < n; ++j)
                        if (su[j] == u_t && ci[j] < myidx) ++r;
                    if (r == krem2 - 1) scut = myidx;
                }
            }
        }
        __syncthreads();
        unsigned cut = scut;
        // scatter-fix selected entries (defaults already written by kB)
        for (unsigned i = t; i < n; i += 256) {
            unsigned u = su[i], idx = ci[i];
            bool sel = (u > u_t) || ((u == u_t) && (idx <= cut));
            if (sel && u > 0x80000000u) { outr[idx] = 1.0f; fbr[idx] = 0.0f; }
        }
    } else {
        // estimate failed (never for this data): exact full-row select + full fix
        unsigned u_t = row_select_full<0>(xr, br, gmax, bp, K, hist, aux, t, &scut);
        unsigned cut = scut;
        for (int i = t; i < EC; i += 256) {
            float nb, bo;
            compute_vals(xr[i], br[i], gmax, bp, &nb, &bo);
            unsigned u = map_f(bo);
            bool sel = (u > u_t) || ((u == u_t) && ((unsigned)i <= cut));
            if (sel && u > 0x80000000u) { outr[i] = 1.0f; fbr[i] = 0.0f; }
        }
    }

    // ---- global active + gated correction branch (dead for this input) ----
    unsigned act = 0;
    if (t < 64) act = umin_(K, ws[WS_NPOS + t]);
    for (int off = 32; off; off >>= 1) act += __shfl_down(act, off, 64);
    if (t == 0) sact = act;
    __syncthreads();
    float active = (float)sact;
    float min_active = floorf(sp[0] * (float)EC);
    if (active < min_active) {
        unsigned K2 = (unsigned)ceilf(min_active - active);
        if (K2 > EC) K2 = EC;
        unsigned ut2 = row_select_full<1>(xr, br, gmax, bp, K2, hist, aux, t, &scut);
        unsigned cut2 = scut;
        for (int i = t; i < EC; i += 256) {
            float nb, bo;
            compute_vals(xr[i], br[i], gmax, bp, &nb, &bo);
            unsigned u2 = map_f(nb);
            if (u2 > ut2 || (u2 == ut2 && (unsigned)i <= cut2)) {
                outr[i] = 1.0f;
                fbr[i] = 0.0f;
            }
        }
    }
}

extern "C" void kernel_launch(void* const* d_in, const int* in_sizes, int n_in,
                              void* d_out, int out_size, void* d_ws, size_t ws_size,
                              hipStream_t stream) {
    const float* x  = (const float*)d_in[0];
    const float* bt = (const float*)d_in[1];
    const float* sp = (const float*)d_in[2];
    const float* bp = (const float*)d_in[3];
    float* out = (float*)d_out;
    float* fb  = out + (size_t)BR * EC;
    unsigned* ws = (unsigned*)d_ws;

    kA<<<1024, 256, 0, stream>>>((const float4*)x, ws);
    kB<<<BR * CHUNKS, BD, 0, stream>>>(x, bt, sp, bp, ws, (nf4*)out, (nf4*)fb);
    kC<<<BR, 256, 0, stream>>>(x, bt, sp, bp, ws, out, fb);
}